// Round 5
// baseline (223.934 us; speedup 1.0000x reference)
//
#include <hip/hip_runtime.h>

// B=2, T=2048, C=1024, H=16, hd=64. fp32 in/out; bf16 MFMA everywhere.
// ws layout (MB offsets):
//   0: qb 8 | 8: kb 8 | 16: vt 8 | 24: xb/yb 8 | 32: woutT 2 |
//   34: vb 8 (dead after transp_v) | 42: wqkvT 6 (dead after gemm_qkv) |
//   34: po 18 MiB (aliases vb+wqkvT; written by attn_p1 only) |
//   52: pm 576K | 52+640K: pl 576K         (total ~53.3 MB)

#define T_SEQ 2048
#define C_DIM 1024
#define NH    16
#define HD    64
#define BT    4096

typedef short bf16x8 __attribute__((ext_vector_type(8)));   // 8 bf16 (4 VGPRs)
typedef float floatx4 __attribute__((ext_vector_type(4)));  // MFMA accum

static __device__ __forceinline__ unsigned short f2bf(float f) {
    union { float f; unsigned u; } v; v.f = f;
    unsigned u = v.u;
    return (unsigned short)((u + 0x7FFFu + ((u >> 16) & 1u)) >> 16);
}
static __device__ __forceinline__ float bf2f(unsigned short u) {
    union { unsigned u; float f; } v; v.u = ((unsigned)u) << 16; return v.f;
}

// async global->LDS, 16B per lane. LDS dest must be wave-uniform base + lane*16.
static __device__ __forceinline__ void gl2lds16(const void* g, void* l) {
    __builtin_amdgcn_global_load_lds(
        (const __attribute__((address_space(1))) unsigned int*)g,
        (__attribute__((address_space(3))) unsigned int*)l, 16, 0, 0);
}

// ---------------- fused prep: x->bf16, W_qkv^T->bf16, W_out^T->bf16 --------
static __device__ __forceinline__ void transpose_body(float (*tile)[65],
                                                      const float* __restrict__ W,
                                                      unsigned short* __restrict__ Wt,
                                                      int K, int N, int bx, int by) {
    const int k0 = by << 6;
    const int n0 = bx << 6;
    const int rr = threadIdx.x >> 4;
    const int cc = (threadIdx.x & 15) << 2;
#pragma unroll
    for (int i = 0; i < 4; i++) {
        int r = rr + (i << 4);
        *(float4*)&tile[r][cc] = *(const float4*)(W + (size_t)(k0 + r) * N + n0 + cc);
    }
    __syncthreads();
#pragma unroll
    for (int i = 0; i < 4; i++) {
        int nr = rr + (i << 4);
        ushort4 o;
        o.x = f2bf(tile[cc + 0][nr]);
        o.y = f2bf(tile[cc + 1][nr]);
        o.z = f2bf(tile[cc + 2][nr]);
        o.w = f2bf(tile[cc + 3][nr]);
        *(ushort4*)(Wt + (size_t)(n0 + nr) * K + k0 + cc) = o;
    }
}

__global__ __launch_bounds__(256) void prep(const float* __restrict__ x,
                                            unsigned short* __restrict__ xb,
                                            const float* __restrict__ w_qkv,
                                            unsigned short* __restrict__ wqkvT,
                                            const float* __restrict__ w_out,
                                            unsigned short* __restrict__ woutT) {
    __shared__ float tile[64][65];
    const int bx = blockIdx.x;
    if (bx < 1024) {                       // convert x (4M floats), 4 sweeps
        int i = (bx * 256 + threadIdx.x) * 4;
        const int n = BT * C_DIM;
        const int stride = 1024 * 1024;
        for (; i < n; i += stride) {
            float4 f = *(const float4*)(x + i);
            ushort4 o;
            o.x = f2bf(f.x); o.y = f2bf(f.y); o.z = f2bf(f.z); o.w = f2bf(f.w);
            *(ushort4*)(xb + i) = o;
        }
    } else if (bx < 1024 + 768) {          // w_qkv [1024][3072] -> [3072][1024]
        int b = bx - 1024;
        transpose_body(tile, w_qkv, wqkvT, 1024, 3072, b % 48, b / 48);
    } else {                               // w_out [1024][1024] -> [1024][1024]
        int b = bx - 1024 - 768;
        transpose_body(tile, w_out, woutT, 1024, 1024, b % 16, b / 16);
    }
}

// ---------------- v [bh][t][d] -> vt [bh][d][t] (LDS tile transpose) -------
__global__ __launch_bounds__(256) void transp_v(const unsigned short* __restrict__ vb,
                                                unsigned short* __restrict__ vt) {
    __shared__ unsigned short tile[64][68];
    const int t0 = blockIdx.x << 6;
    const int bh = blockIdx.y;
    const size_t base = (size_t)bh * T_SEQ * HD;
    const int r = threadIdx.x >> 3;
    const int c = (threadIdx.x & 7) << 3;
#pragma unroll
    for (int i = 0; i < 2; i++) {
        const unsigned short* src = vb + base + (size_t)(t0 + r + (i << 5)) * HD + c;
        ushort4 u0 = *(const ushort4*)src;
        ushort4 u1 = *(const ushort4*)(src + 4);
        *(ushort4*)&tile[r + (i << 5)][c] = u0;
        *(ushort4*)&tile[r + (i << 5)][c + 4] = u1;
    }
    __syncthreads();
#pragma unroll
    for (int i = 0; i < 2; i++) {
        int s = threadIdx.x + (i << 8);
        int d = s >> 3;
        int tc = (s & 7) << 3;
        ushort4 o0, o1;
        o0.x = tile[tc + 0][d]; o0.y = tile[tc + 1][d];
        o0.z = tile[tc + 2][d]; o0.w = tile[tc + 3][d];
        o1.x = tile[tc + 4][d]; o1.y = tile[tc + 5][d];
        o1.z = tile[tc + 6][d]; o1.w = tile[tc + 7][d];
        unsigned short* dst = vt + ((size_t)bh * HD + d) * T_SEQ + t0 + tc;
        *(ushort4*)dst = o0;
        *(ushort4*)(dst + 4) = o1;
    }
}

// ---------------- m97-style bf16 MFMA GEMM core, XOR-swizzled LDS ----------
#define GEMM_CORE(A_, Bt_, K_)                                                      \
    __shared__ short As[128 * 64];                                                  \
    __shared__ short Bs[128 * 64];                                                  \
    const int tid  = threadIdx.x;                                                   \
    const int lane = tid & 63, wave = tid >> 6;                                     \
    const int ln   = lane & 15, quad = lane >> 4;                                   \
    const int wm   = wave & 1,  wn   = wave >> 1;                                   \
    const int row0 = blockIdx.y << 7;                                               \
    const int col0 = blockIdx.x << 7;                                               \
    floatx4 acc[4][4];                                                              \
    _Pragma("unroll")                                                               \
    for (int i = 0; i < 4; i++)                                                     \
        _Pragma("unroll")                                                           \
        for (int j = 0; j < 4; j++) acc[i][j] = (floatx4){0.f, 0.f, 0.f, 0.f};      \
    for (int k0 = 0; k0 < K_; k0 += 64) {                                           \
        _Pragma("unroll")                                                           \
        for (int i = 0; i < 4; i++) {                                               \
            int c = (i << 8) + tid;                                                 \
            int r = c >> 3;                                                         \
            int gsrc = (c & 7) ^ (r & 7);                                           \
            gl2lds16(A_  + (size_t)(row0 + r) * K_ + k0 + (gsrc << 3), &As[c << 3]); \
            gl2lds16(Bt_ + (size_t)(col0 + r) * K_ + k0 + (gsrc << 3), &Bs[c << 3]); \
        }                                                                           \
        __syncthreads();                                                            \
        _Pragma("unroll")                                                           \
        for (int half = 0; half < 2; half++) {                                      \
            bf16x8 af[4], bfr[4];                                                   \
            _Pragma("unroll")                                                       \
            for (int t4 = 0; t4 < 4; t4++) {                                        \
                int ra = (wm << 6) + (t4 << 4) + ln;                                \
                int rb = (wn << 6) + (t4 << 4) + ln;                                \
                int g  = (half << 2) + quad;                                        \
                af[t4]  = *(bf16x8*)&As[((ra << 3) + (g ^ (ra & 7))) << 3];         \
                bfr[t4] = *(bf16x8*)&Bs[((rb << 3) + (g ^ (rb & 7))) << 3];         \
            }                                                                       \
            _Pragma("unroll")                                                       \
            for (int mt = 0; mt < 4; mt++)                                          \
                _Pragma("unroll")                                                   \
                for (int nt = 0; nt < 4; nt++)                                      \
                    acc[mt][nt] = __builtin_amdgcn_mfma_f32_16x16x32_bf16(af[mt], bfr[nt], acc[mt][nt], 0, 0, 0); \
        }                                                                           \
        __syncthreads();                                                            \
    }

// ---------------- GEMM: qkv = X @ WqkvT^T + bias -> bf16 q/k/v (coalesced) --
__global__ __launch_bounds__(256) void gemm_qkv(const unsigned short* __restrict__ A,
                                                const unsigned short* __restrict__ Bt,
                                                const float* __restrict__ bias,
                                                unsigned short* __restrict__ qb,
                                                unsigned short* __restrict__ kb,
                                                unsigned short* __restrict__ vb) {
    GEMM_CORE(A, Bt, 1024)
#pragma unroll
    for (int mt = 0; mt < 4; mt++) {
#pragma unroll
        for (int nt = 0; nt < 4; nt++) {
            int n = col0 + (wn << 6) + (nt << 4) + ln;
            int h = n / 192, r = n % 192;
            int sel = r >> 6, d = r & 63;
            float bv = bias[n];
#pragma unroll
            for (int e = 0; e < 4; e++) {
                int m = row0 + (wm << 6) + (mt << 4) + (quad << 2) + e;
                int b = m >> 11, t = m & 2047;
                float val = acc[mt][nt][e] + bv;
                size_t idx = (((size_t)(b * NH + h)) * T_SEQ + t) * HD + d;
                if (sel == 0)
                    qb[idx] = f2bf(val * 0.125f);
                else if (sel == 1)
                    kb[idx] = f2bf(val);
                else
                    vb[idx] = f2bf(val);
            }
        }
    }
}

// ---------------- GEMM: out = Y @ WoutT^T + bias, 128x64 tile (512 blocks) --
__global__ __launch_bounds__(256) void gemm_out(const unsigned short* __restrict__ A,
                                                const unsigned short* __restrict__ Bt,
                                                const float* __restrict__ bias,
                                                float* __restrict__ out) {
    const int K = 1024, N = 1024;
    __shared__ short As[128 * 64];
    __shared__ short Bs[64 * 64];
    const int tid  = threadIdx.x;
    const int lane = tid & 63, wave = tid >> 6;
    const int ln   = lane & 15, quad = lane >> 4;
    const int wm   = wave & 1,  wn   = wave >> 1;
    const int row0 = blockIdx.y << 7;
    const int col0 = blockIdx.x << 6;
    floatx4 acc[4][2];
#pragma unroll
    for (int i = 0; i < 4; i++)
#pragma unroll
        for (int j = 0; j < 2; j++) acc[i][j] = (floatx4){0.f, 0.f, 0.f, 0.f};
    for (int k0 = 0; k0 < K; k0 += 64) {
#pragma unroll
        for (int i = 0; i < 4; i++) {          // A: 1024 chunks
            int c = (i << 8) + tid;
            int r = c >> 3;
            int gsrc = (c & 7) ^ (r & 7);
            gl2lds16(A + (size_t)(row0 + r) * K + k0 + (gsrc << 3), &As[c << 3]);
        }
#pragma unroll
        for (int i = 0; i < 2; i++) {          // B: 512 chunks
            int c = (i << 8) + tid;
            int r = c >> 3;
            int gsrc = (c & 7) ^ (r & 7);
            gl2lds16(Bt + (size_t)(col0 + r) * K + k0 + (gsrc << 3), &Bs[c << 3]);
        }
        __syncthreads();
#pragma unroll
        for (int half = 0; half < 2; half++) {
            bf16x8 af[4], bfr[2];
#pragma unroll
            for (int t4 = 0; t4 < 4; t4++) {
                int ra = (wm << 6) + (t4 << 4) + ln;
                int g  = (half << 2) + quad;
                af[t4] = *(bf16x8*)&As[((ra << 3) + (g ^ (ra & 7))) << 3];
            }
#pragma unroll
            for (int t2 = 0; t2 < 2; t2++) {
                int rb = (wn << 5) + (t2 << 4) + ln;
                int g  = (half << 2) + quad;
                bfr[t2] = *(bf16x8*)&Bs[((rb << 3) + (g ^ (rb & 7))) << 3];
            }
#pragma unroll
            for (int mt = 0; mt < 4; mt++)
#pragma unroll
                for (int nt = 0; nt < 2; nt++)
                    acc[mt][nt] = __builtin_amdgcn_mfma_f32_16x16x32_bf16(af[mt], bfr[nt], acc[mt][nt], 0, 0, 0);
        }
        __syncthreads();
    }
#pragma unroll
    for (int mt = 0; mt < 4; mt++) {
#pragma unroll
        for (int nt = 0; nt < 2; nt++) {
            int n = col0 + (wn << 5) + (nt << 4) + ln;
            float bv = bias[n];
#pragma unroll
            for (int e = 0; e < 4; e++) {
                int m = row0 + (wm << 6) + (mt << 4) + (quad << 2) + e;
                out[(size_t)m * N + n] = acc[mt][nt][e] + bv;
            }
        }
    }
}

// ---------------- MFMA flash attention pass1: 128-row q-blocks -------------
// Each block handles TWO 64-row q-subtiles (s=0,1) sharing one K/V staging:
// per staged K/V tile the barrier+staging cost is amortized over 2x compute,
// and sub-B's QK MFMAs overlap sub-A's softmax VALU (independent chains).
// qt2 = 0..15 (128 q rows each); kt chunks of <=8 tiles, longest-first:
//   bx<16: c=0, qt2=15-bx | bx<28: c=1, qt2=15-(bx-16) (qt2>=4)
//   bx<36: c=2, qt2=15-(bx-28) (qt2>=8) | else c=3, qt2=15-(bx-36) (qt2>=12)
// nc = (2*qt2+9)>>3 chunks; nc==1 (qt2<=3) finalizes y; else partials at
// slot = bh*36 + cb2(qt2) + c (128 rows/slot), merged by attn_p2.
// Lesson log: (256,6) minwaves -> VGPR cap ~85 -> scratch spills (204MB
// WRITE, r2). r3/r4: occupancy pinned ~28% and dur ~58us regardless of
// residency cap -> serial per-iteration chain is the limiter, hence this
// QBLK=128 amortization. No launch-bounds minwaves (spill canary: WRITE_SIZE).
__global__ __launch_bounds__(256) void attn_p1(const unsigned short* __restrict__ qb,
                                               const unsigned short* __restrict__ kb,
                                               const unsigned short* __restrict__ vt,
                                               unsigned short* __restrict__ y,
                                               unsigned short* __restrict__ po,
                                               float* __restrict__ pm,
                                               float* __restrict__ pl) {
    __shared__ short Ks[64][68];
    __shared__ short Vs[64][68];
    __shared__ short QP[2][64][68];
    const int tid  = threadIdx.x;
    const int w    = tid >> 6, lane = tid & 63;
    const int ln   = lane & 15, quad = lane >> 4;
    const int bx   = blockIdx.x;
    int qt2, c;
    if (bx < 16)      { qt2 = 15 - bx;        c = 0; }
    else if (bx < 28) { qt2 = 15 - (bx - 16); c = 1; }
    else if (bx < 36) { qt2 = 15 - (bx - 28); c = 2; }
    else              { qt2 = 15 - (bx - 36); c = 3; }
    const int kt_lo = c << 3;
    const int qtB   = (qt2 << 1) + 1;
    const int kt_hi = (kt_lo + 7 < qtB) ? (kt_lo + 7) : qtB;
    const int nc    = ((qt2 << 1) + 9) >> 3;   // 1..4
    const bool fin  = (nc == 1);
    const int bh   = blockIdx.y;
    const size_t base = (size_t)bh * T_SEQ * HD;
    const int q0   = qt2 << 7;
    const float NEG_INF = -__builtin_inff();

    const int sr = tid >> 3;
    const int sc = (tid & 7) << 3;

    // Q fragments for both subtiles straight from global
    bf16x8 bq[2][2];
#pragma unroll
    for (int s = 0; s < 2; s++) {
        const unsigned short* qrow = qb + base + (size_t)(q0 + (s << 6) + (w << 4) + ln) * HD;
        bq[s][0] = *(const bf16x8*)(qrow + (quad << 3));
        bq[s][1] = *(const bf16x8*)(qrow + 32 + (quad << 3));
    }

    // prefetch K/V tile kt_lo into regs
    bf16x8 kreg[2], vreg[2];
    const int kk0 = kt_lo << 6;
#pragma unroll
    for (int i = 0; i < 2; i++) {
        kreg[i] = *(const bf16x8*)(kb + base + (size_t)(kk0 + sr + (i << 5)) * HD + sc);
        vreg[i] = *(const bf16x8*)(vt + base + (size_t)(sr + (i << 5)) * T_SEQ + kk0 + sc);
    }

    floatx4 o[2][4];
#pragma unroll
    for (int s = 0; s < 2; s++)
#pragma unroll
        for (int nt = 0; nt < 4; nt++) o[s][nt] = (floatx4){0.f, 0.f, 0.f, 0.f};
    float m_prev[2] = {NEG_INF, NEG_INF};
    float l_run[2]  = {0.f, 0.f};

    for (int kt = kt_lo; kt <= kt_hi; kt++) {
        const int k0 = kt << 6;
        __syncthreads();
#pragma unroll
        for (int i = 0; i < 2; i++) {
            *(bf16x8*)&Ks[sr + (i << 5)][sc] = kreg[i];
            *(bf16x8*)&Vs[sr + (i << 5)][sc] = vreg[i];
        }
        __syncthreads();
        if (kt < kt_hi) {
            const int kn = k0 + 64;
#pragma unroll
            for (int i = 0; i < 2; i++) {
                kreg[i] = *(const bf16x8*)(kb + base + (size_t)(kn + sr + (i << 5)) * HD + sc);
                vreg[i] = *(const bf16x8*)(vt + base + (size_t)(sr + (i << 5)) * T_SEQ + kn + sc);
            }
        }

#pragma unroll
        for (int s = 0; s < 2; s++) {
            const int qts = (qt2 << 1) + s;
            if (kt > qts) continue;               // sub inactive (only s=0, last tile)
            const bool diag  = (kt == qts);
            const int  nlive = diag ? w : 3;
            const int  sb    = q0 + (s << 6) + (w << 4);

            floatx4 st[4];
#pragma unroll
            for (int ktl = 0; ktl < 4; ktl++) {
                if (ktl <= nlive) {
                    bf16x8 a0 = *(bf16x8*)&Ks[(ktl << 4) + ln][quad << 3];
                    bf16x8 a1 = *(bf16x8*)&Ks[(ktl << 4) + ln][32 + (quad << 3)];
                    floatx4 acc = (floatx4){0.f, 0.f, 0.f, 0.f};
                    acc = __builtin_amdgcn_mfma_f32_16x16x32_bf16(a0, bq[s][0], acc, 0, 0, 0);
                    acc = __builtin_amdgcn_mfma_f32_16x16x32_bf16(a1, bq[s][1], acc, 0, 0, 0);
                    st[ktl] = acc;
                }
            }
            if (diag) {
#pragma unroll
                for (int ktl = 0; ktl < 4; ktl++) {
                    if (ktl <= nlive) {
#pragma unroll
                        for (int e = 0; e < 4; e++) {
                            int kg = k0 + (ktl << 4) + (quad << 2) + e;
                            if (kg > sb + ln) st[ktl][e] = NEG_INF;
                        }
                    }
                }
            }

            float mx = NEG_INF;
#pragma unroll
            for (int ktl = 0; ktl < 4; ktl++)
                if (ktl <= nlive) {
#pragma unroll
                    for (int e = 0; e < 4; e++) mx = fmaxf(mx, st[ktl][e]);
                }
            mx = fmaxf(mx, __shfl_xor(mx, 16));
            mx = fmaxf(mx, __shfl_xor(mx, 32));
            float m_new = fmaxf(m_prev[s], mx);
            float alpha = __expf(m_prev[s] - m_new);
            float psum = 0.f;
#pragma unroll
            for (int ktl = 0; ktl < 4; ktl++)
                if (ktl <= nlive) {
#pragma unroll
                    for (int e = 0; e < 4; e++) {
                        float p = __expf(st[ktl][e] - m_new);
                        st[ktl][e] = p;
                        psum += p;
                    }
                }
            psum += __shfl_xor(psum, 16);
            psum += __shfl_xor(psum, 32);
            l_run[s] = l_run[s] * alpha + psum;
            m_prev[s] = m_new;

#pragma unroll
            for (int ktl = 0; ktl < 4; ktl++) {
                ushort4 pw;
                if (ktl <= nlive) {
                    pw.x = f2bf(st[ktl][0]); pw.y = f2bf(st[ktl][1]);
                    pw.z = f2bf(st[ktl][2]); pw.w = f2bf(st[ktl][3]);
                } else {
                    pw.x = 0; pw.y = 0; pw.z = 0; pw.w = 0;
                }
                *(ushort4*)&QP[s][(w << 4) + ln][(ktl << 4) + (quad << 2)] = pw;
            }

            float arow[4];
#pragma unroll
            for (int e = 0; e < 4; e++) arow[e] = __shfl(alpha, (quad << 2) + e);
#pragma unroll
            for (int nt = 0; nt < 4; nt++)
#pragma unroll
                for (int e = 0; e < 4; e++) o[s][nt][e] *= arow[e];

            bf16x8 ap0 = *(bf16x8*)&QP[s][(w << 4) + ln][quad << 3];
            bf16x8 ap1 = *(bf16x8*)&QP[s][(w << 4) + ln][32 + (quad << 3)];
#pragma unroll
            for (int nt = 0; nt < 4; nt++) {
                bf16x8 v0 = *(bf16x8*)&Vs[(nt << 4) + ln][quad << 3];
                bf16x8 v1 = *(bf16x8*)&Vs[(nt << 4) + ln][32 + (quad << 3)];
                o[s][nt] = __builtin_amdgcn_mfma_f32_16x16x32_bf16(ap0, v0, o[s][nt], 0, 0, 0);
                o[s][nt] = __builtin_amdgcn_mfma_f32_16x16x32_bf16(ap1, v1, o[s][nt], 0, 0, 0);
            }
        }
    }

    if (fin) {
        // final epilogue: y[b, t, h*64+d] bf16, both subtiles
        const int b = bh >> 4, h = bh & 15;
#pragma unroll
        for (int s = 0; s < 2; s++) {
            float linv[4];
#pragma unroll
            for (int e = 0; e < 4; e++) linv[e] = 1.0f / __shfl(l_run[s], (quad << 2) + e);
#pragma unroll
            for (int e = 0; e < 4; e++) {
                int t = q0 + (s << 6) + (w << 4) + (quad << 2) + e;
                unsigned short* yrow = y + ((size_t)b * T_SEQ + t) * C_DIM + h * HD;
#pragma unroll
                for (int nt = 0; nt < 4; nt++)
                    yrow[(nt << 4) + ln] = f2bf(o[s][nt][e] * linv[e]);
            }
        }
    } else {
        // partial epilogue: unnormalized o (bf16, 128 rows) + m,l (fp32)
        int cb;
        if (qt2 < 8)       cb = (qt2 - 4) * 2;
        else if (qt2 < 12) cb = 8 + (qt2 - 8) * 3;
        else               cb = 20 + (qt2 - 12) * 4;
        const int slot = bh * 36 + cb + c;                 // 0..1151
#pragma unroll
        for (int s = 0; s < 2; s++) {
            if (quad == 0) {
                pm[(slot << 7) + (s << 6) + (w << 4) + ln] = m_prev[s];
                pl[(slot << 7) + (s << 6) + (w << 4) + ln] = l_run[s];
            }
#pragma unroll
            for (int e = 0; e < 4; e++) {
                int r = (s << 6) + (w << 4) + (quad << 2) + e;
                unsigned short* porow = po + ((size_t)slot << 13) + (r << 6);
#pragma unroll
                for (int nt = 0; nt < 4; nt++)
                    porow[(nt << 4) + ln] = f2bf(o[s][nt][e]);
            }
        }
    }
}

// ---------------- attn pass2: merge 2..4 chunks for qt2>=4 -----------------
__global__ __launch_bounds__(256) void attn_p2(const unsigned short* __restrict__ po,
                                               const float* __restrict__ pm,
                                               const float* __restrict__ pl,
                                               unsigned short* __restrict__ y) {
    const int qt2 = 4 + blockIdx.x;           // 4..15
    const int bh  = blockIdx.y;
    const int nc  = ((qt2 << 1) + 9) >> 3;    // 2..4
    int cb;
    if (qt2 < 8)       cb = (qt2 - 4) * 2;
    else if (qt2 < 12) cb = 8 + (qt2 - 8) * 3;
    else               cb = 20 + (qt2 - 12) * 4;
    const int slot0 = bh * 36 + cb;
    const int tid = threadIdx.x;
    const int d0  = (tid & 3) << 4;
    const int b = bh >> 4, h = bh & 15;
    const float NEG_INF = -__builtin_inff();

#pragma unroll
    for (int qh = 0; qh < 2; qh++) {
        const int q = (tid >> 2) + (qh << 6);     // 0..127
        float mv[4], lv[4];
#pragma unroll
        for (int cc = 0; cc < 4; cc++) {
            if (cc < nc) {
                mv[cc] = pm[((slot0 + cc) << 7) + q];
                lv[cc] = pl[((slot0 + cc) << 7) + q];
            } else {
                mv[cc] = NEG_INF; lv[cc] = 0.f;
            }
        }
        float m = fmaxf(fmaxf(mv[0], mv[1]), fmaxf(mv[2], mv[3]));
        float a[4];
        float L = 0.f;
#pragma unroll
        for (int cc = 0; cc < 4; cc++) {
            a[cc] = __expf(mv[cc] - m);
            L += lv[cc] * a[cc];
        }
        const float inv = 1.0f / L;
#pragma unroll
        for (int cc = 0; cc < 4; cc++) a[cc] *= inv;

        float acc[16];
#pragma unroll
        for (int i = 0; i < 16; i++) acc[i] = 0.f;
#pragma unroll
        for (int cc = 0; cc < 4; cc++) {
            if (cc < nc) {
                const unsigned short* r = po + ((size_t)(slot0 + cc) << 13) + (q << 6) + d0;
                const float ac = a[cc];
#pragma unroll
                for (int i = 0; i < 4; i++) {
                    ushort4 u = *(const ushort4*)(r + (i << 2));
                    acc[(i << 2) + 0] += ac * bf2f(u.x);
                    acc[(i << 2) + 1] += ac * bf2f(u.y);
                    acc[(i << 2) + 2] += ac * bf2f(u.z);
                    acc[(i << 2) + 3] += ac * bf2f(u.w);
                }
            }
        }

        const int t = (qt2 << 7) + q;
        unsigned short* yrow = y + ((size_t)b * T_SEQ + t) * C_DIM + h * HD + d0;
#pragma unroll
        for (int i = 0; i < 4; i++) {
            ushort4 ow;
            ow.x = f2bf(acc[(i << 2) + 0]);
            ow.y = f2bf(acc[(i << 2) + 1]);
            ow.z = f2bf(acc[(i << 2) + 2]);
            ow.w = f2bf(acc[(i << 2) + 3]);
            *(ushort4*)(yrow + (i << 2)) = ow;
        }
    }
}

extern "C" void kernel_launch(void* const* d_in, const int* in_sizes, int n_in,
                              void* d_out, int out_size, void* d_ws, size_t ws_size,
                              hipStream_t stream) {
    (void)in_sizes; (void)n_in; (void)out_size; (void)ws_size;
    const float* x     = (const float*)d_in[0];
    const float* w_qkv = (const float*)d_in[1];
    const float* b_qkv = (const float*)d_in[2];
    const float* w_out = (const float*)d_in[3];
    const float* b_out = (const float*)d_in[4];
    float* out = (float*)d_out;

    char* ws = (char*)d_ws;
    unsigned short* qb    = (unsigned short*)ws;                        // 8 MB
    unsigned short* kb    = (unsigned short*)(ws + ((size_t)8  << 20)); // 8 MB
    unsigned short* vt    = (unsigned short*)(ws + ((size_t)16 << 20)); // 8 MB
    unsigned short* xb    = (unsigned short*)(ws + ((size_t)24 << 20)); // 8 MB (alias yb)
    unsigned short* yb    = xb;
    unsigned short* woutT = (unsigned short*)(ws + ((size_t)32 << 20)); // 2 MB
    unsigned short* vb    = (unsigned short*)(ws + ((size_t)34 << 20)); // 8 MB (dead after transp_v)
    unsigned short* wqkvT = (unsigned short*)(ws + ((size_t)42 << 20)); // 6 MB (dead after gemm_qkv)
    unsigned short* po    = (unsigned short*)(ws + ((size_t)34 << 20)); // 18 MB, aliases vb+wqkvT
    float*          pm    = (float*)(ws + ((size_t)52 << 20));          // 576 KB
    float*          pl    = (float*)(ws + ((size_t)52 << 20) + (640 << 10)); // 576 KB

    prep    <<<2048, 256, 0, stream>>>(x, xb, w_qkv, wqkvT, w_out, woutT);
    gemm_qkv<<<dim3(24, 32), 256, 0, stream>>>(xb, wqkvT, b_qkv, qb, kb, vb);
    transp_v<<<dim3(32, 32), 256, 0, stream>>>(vb, vt);
    attn_p1 <<<dim3(40, 32), 256, 0, stream>>>(qb, kb, vt, yb, po, pm, pl);
    attn_p2 <<<dim3(12, 32), 256, 0, stream>>>(po, pm, pl, yb);
    gemm_out<<<dim3(16, 32), 256, 0, stream>>>(yb, woutT, b_out, out);
}

// Round 6
// 204.723 us; speedup vs baseline: 1.0938x; 1.0938x over previous
//
#include <hip/hip_runtime.h>

// B=2, T=2048, C=1024, H=16, hd=64. fp32 in/out; bf16 MFMA everywhere.
// ws layout (MB offsets):
//   0: qb 8 | 8: kb 8 | 16: vt 8 | 24: xb/yb 8 | 32: woutT 2 |
//   34: vb 8 (dead after transp_v) | 42: wqkvT 6 (dead after gemm_qkv) |
//   34: po 18 MiB (aliases vb+wqkvT; written by attn_p1 only) |
//   52: pm 576K | 52+640K: pl 576K         (total ~53.3 MB)
// NOTE: softmax runs in base-2 domain (q pre-scaled by 0.125*log2e in
// gemm_qkv); exp = v_exp_f32 (2^x) directly, incl. attn_p2 merge.

#define T_SEQ 2048
#define C_DIM 1024
#define NH    16
#define HD    64
#define BT    4096

typedef short bf16x8 __attribute__((ext_vector_type(8)));   // 8 bf16 (4 VGPRs)
typedef float floatx4 __attribute__((ext_vector_type(4)));  // MFMA accum

static __device__ __forceinline__ unsigned short f2bf(float f) {
    union { float f; unsigned u; } v; v.f = f;
    unsigned u = v.u;
    return (unsigned short)((u + 0x7FFFu + ((u >> 16) & 1u)) >> 16);
}
static __device__ __forceinline__ float bf2f(unsigned short u) {
    union { unsigned u; float f; } v; v.u = ((unsigned)u) << 16; return v.f;
}
// 2^x via the TRANS pipe, no log2e pre-multiply
static __device__ __forceinline__ float exp2_fast(float x) {
    float r; asm("v_exp_f32 %0, %1" : "=v"(r) : "v"(x)); return r;
}
// pack two f32 -> 2xbf16 (RNE) in one instruction
static __device__ __forceinline__ unsigned cvt_pk_bf16(float lo, float hi) {
    unsigned r; asm("v_cvt_pk_bf16_f32 %0, %1, %2" : "=v"(r) : "v"(lo), "v"(hi)); return r;
}

// async global->LDS, 16B per lane. LDS dest must be wave-uniform base + lane*16.
static __device__ __forceinline__ void gl2lds16(const void* g, void* l) {
    __builtin_amdgcn_global_load_lds(
        (const __attribute__((address_space(1))) unsigned int*)g,
        (__attribute__((address_space(3))) unsigned int*)l, 16, 0, 0);
}

// ---------------- fused prep: x->bf16, W_qkv^T->bf16, W_out^T->bf16 --------
static __device__ __forceinline__ void transpose_body(float (*tile)[65],
                                                      const float* __restrict__ W,
                                                      unsigned short* __restrict__ Wt,
                                                      int K, int N, int bx, int by) {
    const int k0 = by << 6;
    const int n0 = bx << 6;
    const int rr = threadIdx.x >> 4;
    const int cc = (threadIdx.x & 15) << 2;
#pragma unroll
    for (int i = 0; i < 4; i++) {
        int r = rr + (i << 4);
        *(float4*)&tile[r][cc] = *(const float4*)(W + (size_t)(k0 + r) * N + n0 + cc);
    }
    __syncthreads();
#pragma unroll
    for (int i = 0; i < 4; i++) {
        int nr = rr + (i << 4);
        ushort4 o;
        o.x = f2bf(tile[cc + 0][nr]);
        o.y = f2bf(tile[cc + 1][nr]);
        o.z = f2bf(tile[cc + 2][nr]);
        o.w = f2bf(tile[cc + 3][nr]);
        *(ushort4*)(Wt + (size_t)(n0 + nr) * K + k0 + cc) = o;
    }
}

__global__ __launch_bounds__(256) void prep(const float* __restrict__ x,
                                            unsigned short* __restrict__ xb,
                                            const float* __restrict__ w_qkv,
                                            unsigned short* __restrict__ wqkvT,
                                            const float* __restrict__ w_out,
                                            unsigned short* __restrict__ woutT) {
    __shared__ float tile[64][65];
    const int bx = blockIdx.x;
    if (bx < 1024) {                       // convert x (4M floats), 4 sweeps
        int i = (bx * 256 + threadIdx.x) * 4;
        const int n = BT * C_DIM;
        const int stride = 1024 * 1024;
        for (; i < n; i += stride) {
            float4 f = *(const float4*)(x + i);
            ushort4 o;
            o.x = f2bf(f.x); o.y = f2bf(f.y); o.z = f2bf(f.z); o.w = f2bf(f.w);
            *(ushort4*)(xb + i) = o;
        }
    } else if (bx < 1024 + 768) {          // w_qkv [1024][3072] -> [3072][1024]
        int b = bx - 1024;
        transpose_body(tile, w_qkv, wqkvT, 1024, 3072, b % 48, b / 48);
    } else {                               // w_out [1024][1024] -> [1024][1024]
        int b = bx - 1024 - 768;
        transpose_body(tile, w_out, woutT, 1024, 1024, b % 16, b / 16);
    }
}

// ---------------- v [bh][t][d] -> vt [bh][d][t] (LDS tile transpose) -------
__global__ __launch_bounds__(256) void transp_v(const unsigned short* __restrict__ vb,
                                                unsigned short* __restrict__ vt) {
    __shared__ unsigned short tile[64][68];
    const int t0 = blockIdx.x << 6;
    const int bh = blockIdx.y;
    const size_t base = (size_t)bh * T_SEQ * HD;
    const int r = threadIdx.x >> 3;
    const int c = (threadIdx.x & 7) << 3;
#pragma unroll
    for (int i = 0; i < 2; i++) {
        const unsigned short* src = vb + base + (size_t)(t0 + r + (i << 5)) * HD + c;
        ushort4 u0 = *(const ushort4*)src;
        ushort4 u1 = *(const ushort4*)(src + 4);
        *(ushort4*)&tile[r + (i << 5)][c] = u0;
        *(ushort4*)&tile[r + (i << 5)][c + 4] = u1;
    }
    __syncthreads();
#pragma unroll
    for (int i = 0; i < 2; i++) {
        int s = threadIdx.x + (i << 8);
        int d = s >> 3;
        int tc = (s & 7) << 3;
        ushort4 o0, o1;
        o0.x = tile[tc + 0][d]; o0.y = tile[tc + 1][d];
        o0.z = tile[tc + 2][d]; o0.w = tile[tc + 3][d];
        o1.x = tile[tc + 4][d]; o1.y = tile[tc + 5][d];
        o1.z = tile[tc + 6][d]; o1.w = tile[tc + 7][d];
        unsigned short* dst = vt + ((size_t)bh * HD + d) * T_SEQ + t0 + tc;
        *(ushort4*)dst = o0;
        *(ushort4*)(dst + 4) = o1;
    }
}

// ---------------- m97-style bf16 MFMA GEMM core, XOR-swizzled LDS ----------
#define GEMM_CORE(A_, Bt_, K_)                                                      \
    __shared__ short As[128 * 64];                                                  \
    __shared__ short Bs[128 * 64];                                                  \
    const int tid  = threadIdx.x;                                                   \
    const int lane = tid & 63, wave = tid >> 6;                                     \
    const int ln   = lane & 15, quad = lane >> 4;                                   \
    const int wm   = wave & 1,  wn   = wave >> 1;                                   \
    const int row0 = blockIdx.y << 7;                                               \
    const int col0 = blockIdx.x << 7;                                               \
    floatx4 acc[4][4];                                                              \
    _Pragma("unroll")                                                               \
    for (int i = 0; i < 4; i++)                                                     \
        _Pragma("unroll")                                                           \
        for (int j = 0; j < 4; j++) acc[i][j] = (floatx4){0.f, 0.f, 0.f, 0.f};      \
    for (int k0 = 0; k0 < K_; k0 += 64) {                                           \
        _Pragma("unroll")                                                           \
        for (int i = 0; i < 4; i++) {                                               \
            int c = (i << 8) + tid;                                                 \
            int r = c >> 3;                                                         \
            int gsrc = (c & 7) ^ (r & 7);                                           \
            gl2lds16(A_  + (size_t)(row0 + r) * K_ + k0 + (gsrc << 3), &As[c << 3]); \
            gl2lds16(Bt_ + (size_t)(col0 + r) * K_ + k0 + (gsrc << 3), &Bs[c << 3]); \
        }                                                                           \
        __syncthreads();                                                            \
        _Pragma("unroll")                                                           \
        for (int half = 0; half < 2; half++) {                                      \
            bf16x8 af[4], bfr[4];                                                   \
            _Pragma("unroll")                                                       \
            for (int t4 = 0; t4 < 4; t4++) {                                        \
                int ra = (wm << 6) + (t4 << 4) + ln;                                \
                int rb = (wn << 6) + (t4 << 4) + ln;                                \
                int g  = (half << 2) + quad;                                        \
                af[t4]  = *(bf16x8*)&As[((ra << 3) + (g ^ (ra & 7))) << 3];         \
                bfr[t4] = *(bf16x8*)&Bs[((rb << 3) + (g ^ (rb & 7))) << 3];         \
            }                                                                       \
            _Pragma("unroll")                                                       \
            for (int mt = 0; mt < 4; mt++)                                          \
                _Pragma("unroll")                                                   \
                for (int nt = 0; nt < 4; nt++)                                      \
                    acc[mt][nt] = __builtin_amdgcn_mfma_f32_16x16x32_bf16(af[mt], bfr[nt], acc[mt][nt], 0, 0, 0); \
        }                                                                           \
        __syncthreads();                                                            \
    }

// ---------------- GEMM: qkv = X @ WqkvT^T + bias -> bf16 q/k/v (coalesced) --
// q is scaled by 0.125*log2(e) so attention softmax can use 2^x directly.
__global__ __launch_bounds__(256) void gemm_qkv(const unsigned short* __restrict__ A,
                                                const unsigned short* __restrict__ Bt,
                                                const float* __restrict__ bias,
                                                unsigned short* __restrict__ qb,
                                                unsigned short* __restrict__ kb,
                                                unsigned short* __restrict__ vb) {
    GEMM_CORE(A, Bt, 1024)
    const float QSCALE = 0.125f * 1.4426950408889634f;
#pragma unroll
    for (int mt = 0; mt < 4; mt++) {
#pragma unroll
        for (int nt = 0; nt < 4; nt++) {
            int n = col0 + (wn << 6) + (nt << 4) + ln;
            int h = n / 192, r = n % 192;
            int sel = r >> 6, d = r & 63;
            float bv = bias[n];
#pragma unroll
            for (int e = 0; e < 4; e++) {
                int m = row0 + (wm << 6) + (mt << 4) + (quad << 2) + e;
                int b = m >> 11, t = m & 2047;
                float val = acc[mt][nt][e] + bv;
                size_t idx = (((size_t)(b * NH + h)) * T_SEQ + t) * HD + d;
                if (sel == 0)
                    qb[idx] = f2bf(val * QSCALE);
                else if (sel == 1)
                    kb[idx] = f2bf(val);
                else
                    vb[idx] = f2bf(val);
            }
        }
    }
}

// ---------------- GEMM: out = Y @ WoutT^T + bias, 128x64 tile (512 blocks) --
__global__ __launch_bounds__(256) void gemm_out(const unsigned short* __restrict__ A,
                                                const unsigned short* __restrict__ Bt,
                                                const float* __restrict__ bias,
                                                float* __restrict__ out) {
    const int K = 1024, N = 1024;
    __shared__ short As[128 * 64];
    __shared__ short Bs[64 * 64];
    const int tid  = threadIdx.x;
    const int lane = tid & 63, wave = tid >> 6;
    const int ln   = lane & 15, quad = lane >> 4;
    const int wm   = wave & 1,  wn   = wave >> 1;
    const int row0 = blockIdx.y << 7;
    const int col0 = blockIdx.x << 6;
    floatx4 acc[4][2];
#pragma unroll
    for (int i = 0; i < 4; i++)
#pragma unroll
        for (int j = 0; j < 2; j++) acc[i][j] = (floatx4){0.f, 0.f, 0.f, 0.f};
    for (int k0 = 0; k0 < K; k0 += 64) {
#pragma unroll
        for (int i = 0; i < 4; i++) {          // A: 1024 chunks
            int c = (i << 8) + tid;
            int r = c >> 3;
            int gsrc = (c & 7) ^ (r & 7);
            gl2lds16(A + (size_t)(row0 + r) * K + k0 + (gsrc << 3), &As[c << 3]);
        }
#pragma unroll
        for (int i = 0; i < 2; i++) {          // B: 512 chunks
            int c = (i << 8) + tid;
            int r = c >> 3;
            int gsrc = (c & 7) ^ (r & 7);
            gl2lds16(Bt + (size_t)(col0 + r) * K + k0 + (gsrc << 3), &Bs[c << 3]);
        }
        __syncthreads();
#pragma unroll
        for (int half = 0; half < 2; half++) {
            bf16x8 af[4], bfr[2];
#pragma unroll
            for (int t4 = 0; t4 < 4; t4++) {
                int ra = (wm << 6) + (t4 << 4) + ln;
                int g  = (half << 2) + quad;
                af[t4] = *(bf16x8*)&As[((ra << 3) + (g ^ (ra & 7))) << 3];
            }
#pragma unroll
            for (int t2 = 0; t2 < 2; t2++) {
                int rb = (wn << 5) + (t2 << 4) + ln;
                int g  = (half << 2) + quad;
                bfr[t2] = *(bf16x8*)&Bs[((rb << 3) + (g ^ (rb & 7))) << 3];
            }
#pragma unroll
            for (int mt = 0; mt < 4; mt++)
#pragma unroll
                for (int nt = 0; nt < 2; nt++)
                    acc[mt][nt] = __builtin_amdgcn_mfma_f32_16x16x32_bf16(af[mt], bfr[nt], acc[mt][nt], 0, 0, 0);
        }
        __syncthreads();
    }
#pragma unroll
    for (int mt = 0; mt < 4; mt++) {
#pragma unroll
        for (int nt = 0; nt < 2; nt++) {
            int n = col0 + (wn << 5) + (nt << 4) + ln;
            float bv = bias[n];
#pragma unroll
            for (int e = 0; e < 4; e++) {
                int m = row0 + (wm << 6) + (mt << 4) + (quad << 2) + e;
                out[(size_t)m * N + n] = acc[mt][nt][e] + bv;
            }
        }
    }
}

// ---------------- MFMA flash attention pass1: uniform 8-tile chunks --------
// r3 structure (best known: 57.4us). This round: VALU diet only —
// base-2 softmax (v_exp_f32 direct), v_cvt_pk_bf16_f32 P-pack,
// defer-rescale when running max doesn't grow, s_setprio around MFMA.
// Lessons: (256,6) -> spills (r2); residency knobs don't move dur (r3/r4);
// QBLK=128 regressed (r5: VALU chains don't overlap, occupancy fell).
__global__ __launch_bounds__(256, 4) void attn_p1(const unsigned short* __restrict__ qb,
                                                  const unsigned short* __restrict__ kb,
                                                  const unsigned short* __restrict__ vt,
                                                  unsigned short* __restrict__ y,
                                                  unsigned short* __restrict__ po,
                                                  float* __restrict__ pm,
                                                  float* __restrict__ pl) {
    __shared__ short Ks[64][68];
    __shared__ short Vs[64][68];
    __shared__ short QP[64][68];
    const int tid  = threadIdx.x;
    const int w    = tid >> 6, lane = tid & 63;
    const int ln   = lane & 15, quad = lane >> 4;
    const int bx   = blockIdx.x;
    int qt, c;
    if (bx < 32)      { qt = 31 - bx;        c = 0; }
    else if (bx < 56) { qt = 31 - (bx - 32); c = 1; }
    else if (bx < 72) { qt = 31 - (bx - 56); c = 2; }
    else              { qt = 31 - (bx - 72); c = 3; }
    const int kt_lo = c << 3;
    const int kt_hi = (kt_lo + 7 < qt) ? (kt_lo + 7) : qt;
    const int nc    = (qt >> 3) + 1;
    const bool fin  = (nc == 1);
    const int bh   = blockIdx.y;
    const size_t base = (size_t)bh * T_SEQ * HD;
    const int q0   = qt << 6;
    const int sb   = q0 + (w << 4);
    const float NEG_INF = -__builtin_inff();

    const int sr = tid >> 3;
    const int sc = (tid & 7) << 3;

    // Q fragments straight from global (no LDS staging / extra barrier)
    const unsigned short* qrow = qb + base + (size_t)(q0 + (w << 4) + ln) * HD;
    bf16x8 bq0 = *(const bf16x8*)(qrow + (quad << 3));
    bf16x8 bq1 = *(const bf16x8*)(qrow + 32 + (quad << 3));

    // prefetch K/V tile kt_lo into regs
    bf16x8 kreg[2], vreg[2];
    const int kk0 = kt_lo << 6;
#pragma unroll
    for (int i = 0; i < 2; i++) {
        kreg[i] = *(const bf16x8*)(kb + base + (size_t)(kk0 + sr + (i << 5)) * HD + sc);
        vreg[i] = *(const bf16x8*)(vt + base + (size_t)(sr + (i << 5)) * T_SEQ + kk0 + sc);
    }

    floatx4 o[4];
#pragma unroll
    for (int nt = 0; nt < 4; nt++) o[nt] = (floatx4){0.f, 0.f, 0.f, 0.f};
    float m_prev = NEG_INF, l_run = 0.f;

    for (int kt = kt_lo; kt <= kt_hi; kt++) {
        const int k0 = kt << 6;
        __syncthreads();
#pragma unroll
        for (int i = 0; i < 2; i++) {
            *(bf16x8*)&Ks[sr + (i << 5)][sc] = kreg[i];
            *(bf16x8*)&Vs[sr + (i << 5)][sc] = vreg[i];
        }
        __syncthreads();
        if (kt < kt_hi) {
            const int kn = k0 + 64;
#pragma unroll
            for (int i = 0; i < 2; i++) {
                kreg[i] = *(const bf16x8*)(kb + base + (size_t)(kn + sr + (i << 5)) * HD + sc);
                vreg[i] = *(const bf16x8*)(vt + base + (size_t)(sr + (i << 5)) * T_SEQ + kn + sc);
            }
        }

        const bool diag  = (kt == qt);
        const int  nlive = diag ? w : 3;

        floatx4 st[4];
        __builtin_amdgcn_s_setprio(1);
#pragma unroll
        for (int ktl = 0; ktl < 4; ktl++) {
            if (ktl <= nlive) {
                bf16x8 a0 = *(bf16x8*)&Ks[(ktl << 4) + ln][quad << 3];
                bf16x8 a1 = *(bf16x8*)&Ks[(ktl << 4) + ln][32 + (quad << 3)];
                floatx4 acc = (floatx4){0.f, 0.f, 0.f, 0.f};
                acc = __builtin_amdgcn_mfma_f32_16x16x32_bf16(a0, bq0, acc, 0, 0, 0);
                acc = __builtin_amdgcn_mfma_f32_16x16x32_bf16(a1, bq1, acc, 0, 0, 0);
                st[ktl] = acc;
            }
        }
        __builtin_amdgcn_s_setprio(0);
        if (diag) {
#pragma unroll
            for (int ktl = 0; ktl < 4; ktl++) {
                if (ktl <= nlive) {
#pragma unroll
                    for (int e = 0; e < 4; e++) {
                        int kg = k0 + (ktl << 4) + (quad << 2) + e;
                        if (kg > sb + ln) st[ktl][e] = NEG_INF;
                    }
                }
            }
        }

        float mx = NEG_INF;
#pragma unroll
        for (int ktl = 0; ktl < 4; ktl++)
            if (ktl <= nlive) {
                mx = fmaxf(mx, fmaxf(fmaxf(st[ktl][0], st[ktl][1]),
                                     fmaxf(st[ktl][2], st[ktl][3])));
            }
        mx = fmaxf(mx, __shfl_xor(mx, 16));
        mx = fmaxf(mx, __shfl_xor(mx, 32));
        const bool need = __any(mx > m_prev);
        const float m_new = fmaxf(m_prev, mx);
        float psum = 0.f;
#pragma unroll
        for (int ktl = 0; ktl < 4; ktl++)
            if (ktl <= nlive) {
#pragma unroll
                for (int e = 0; e < 4; e++) {
                    float p = exp2_fast(st[ktl][e] - m_new);   // base-2 domain
                    st[ktl][e] = p;
                    psum += p;
                }
            }
        psum += __shfl_xor(psum, 16);
        psum += __shfl_xor(psum, 32);

#pragma unroll
        for (int ktl = 0; ktl < 4; ktl++) {
            uint2 pw;
            if (ktl <= nlive) {
                pw.x = cvt_pk_bf16(st[ktl][0], st[ktl][1]);
                pw.y = cvt_pk_bf16(st[ktl][2], st[ktl][3]);
            } else {
                pw.x = 0; pw.y = 0;
            }
            *(uint2*)&QP[(w << 4) + ln][(ktl << 4) + (quad << 2)] = pw;
        }

        if (need) {                       // rescale only when max grew
            float alpha = exp2_fast(m_prev - m_new);
            float arow[4];
#pragma unroll
            for (int e = 0; e < 4; e++) arow[e] = __shfl(alpha, (quad << 2) + e);
#pragma unroll
            for (int nt = 0; nt < 4; nt++)
#pragma unroll
                for (int e = 0; e < 4; e++) o[nt][e] *= arow[e];
            l_run = l_run * alpha + psum;
            m_prev = m_new;
        } else {
            l_run += psum;
        }

        bf16x8 ap0 = *(bf16x8*)&QP[(w << 4) + ln][quad << 3];
        bf16x8 ap1 = *(bf16x8*)&QP[(w << 4) + ln][32 + (quad << 3)];
        __builtin_amdgcn_s_setprio(1);
#pragma unroll
        for (int nt = 0; nt < 4; nt++) {
            bf16x8 v0 = *(bf16x8*)&Vs[(nt << 4) + ln][quad << 3];
            bf16x8 v1 = *(bf16x8*)&Vs[(nt << 4) + ln][32 + (quad << 3)];
            o[nt] = __builtin_amdgcn_mfma_f32_16x16x32_bf16(ap0, v0, o[nt], 0, 0, 0);
            o[nt] = __builtin_amdgcn_mfma_f32_16x16x32_bf16(ap1, v1, o[nt], 0, 0, 0);
        }
        __builtin_amdgcn_s_setprio(0);
    }

    if (fin) {
        // final epilogue: y[b, t, h*64+d] bf16
        float linv[4];
#pragma unroll
        for (int e = 0; e < 4; e++) linv[e] = 1.0f / __shfl(l_run, (quad << 2) + e);
        const int b = bh >> 4, h = bh & 15;
#pragma unroll
        for (int e = 0; e < 4; e++) {
            int t = sb + (quad << 2) + e;
            unsigned short* yrow = y + ((size_t)b * T_SEQ + t) * C_DIM + h * HD;
#pragma unroll
            for (int nt = 0; nt < 4; nt++)
                yrow[(nt << 4) + ln] = f2bf(o[nt][e] * linv[e]);
        }
    } else {
        // partial epilogue: unnormalized o (bf16) + m,l (fp32, base-2 m)
        int cb;
        if (qt < 16)      cb = (qt - 8) * 2;
        else if (qt < 24) cb = 16 + (qt - 16) * 3;
        else              cb = 40 + (qt - 24) * 4;
        const int slot = bh * 72 + cb + c;                 // 0..2303
        if (quad == 0) {
            pm[(slot << 6) + (w << 4) + ln] = m_prev;
            pl[(slot << 6) + (w << 4) + ln] = l_run;
        }
#pragma unroll
        for (int e = 0; e < 4; e++) {
            int q = (w << 4) + (quad << 2) + e;
            unsigned short* porow = po + (((size_t)slot << 6) + q) * HD;
#pragma unroll
            for (int nt = 0; nt < 4; nt++)
                porow[(nt << 4) + ln] = f2bf(o[nt][e]);
        }
    }
}

// ---------------- attn pass2: merge 2..4 chunks for qt>=8 (base-2 m) -------
__global__ __launch_bounds__(256) void attn_p2(const unsigned short* __restrict__ po,
                                               const float* __restrict__ pm,
                                               const float* __restrict__ pl,
                                               unsigned short* __restrict__ y) {
    const int qt = 8 + blockIdx.x;            // 8..31
    const int bh = blockIdx.y;
    const int nc = (qt >> 3) + 1;             // 2..4
    int cb;
    if (qt < 16)      cb = (qt - 8) * 2;
    else if (qt < 24) cb = 16 + (qt - 16) * 3;
    else              cb = 40 + (qt - 24) * 4;
    const int slot0 = bh * 72 + cb;
    const int tid = threadIdx.x;
    const int q  = tid >> 2;
    const int d0 = (tid & 3) << 4;
    const float NEG_INF = -__builtin_inff();

    float mv[4], lv[4];
#pragma unroll
    for (int cc = 0; cc < 4; cc++) {
        if (cc < nc) {
            mv[cc] = pm[((slot0 + cc) << 6) + q];
            lv[cc] = pl[((slot0 + cc) << 6) + q];
        } else {
            mv[cc] = NEG_INF; lv[cc] = 0.f;
        }
    }
    float m = fmaxf(fmaxf(mv[0], mv[1]), fmaxf(mv[2], mv[3]));
    float a[4];
    float L = 0.f;
#pragma unroll
    for (int cc = 0; cc < 4; cc++) {
        a[cc] = (cc < nc) ? exp2_fast(mv[cc] - m) : 0.f;
        L += lv[cc] * a[cc];
    }
    const float inv = 1.0f / L;
#pragma unroll
    for (int cc = 0; cc < 4; cc++) a[cc] *= inv;

    float acc[16];
#pragma unroll
    for (int i = 0; i < 16; i++) acc[i] = 0.f;
#pragma unroll
    for (int cc = 0; cc < 4; cc++) {
        if (cc < nc) {
            const unsigned short* r = po + (((size_t)(slot0 + cc)) << 12) + (q << 6) + d0;
            const float ac = a[cc];
#pragma unroll
            for (int i = 0; i < 4; i++) {
                ushort4 u = *(const ushort4*)(r + (i << 2));
                acc[(i << 2) + 0] += ac * bf2f(u.x);
                acc[(i << 2) + 1] += ac * bf2f(u.y);
                acc[(i << 2) + 2] += ac * bf2f(u.z);
                acc[(i << 2) + 3] += ac * bf2f(u.w);
            }
        }
    }

    const int b = bh >> 4, h = bh & 15;
    const int t = (qt << 6) + q;
    unsigned short* yrow = y + ((size_t)b * T_SEQ + t) * C_DIM + h * HD + d0;
#pragma unroll
    for (int i = 0; i < 4; i++) {
        ushort4 ow;
        ow.x = f2bf(acc[(i << 2) + 0]);
        ow.y = f2bf(acc[(i << 2) + 1]);
        ow.z = f2bf(acc[(i << 2) + 2]);
        ow.w = f2bf(acc[(i << 2) + 3]);
        *(ushort4*)(yrow + (i << 2)) = ow;
    }
}

extern "C" void kernel_launch(void* const* d_in, const int* in_sizes, int n_in,
                              void* d_out, int out_size, void* d_ws, size_t ws_size,
                              hipStream_t stream) {
    (void)in_sizes; (void)n_in; (void)out_size; (void)ws_size;
    const float* x     = (const float*)d_in[0];
    const float* w_qkv = (const float*)d_in[1];
    const float* b_qkv = (const float*)d_in[2];
    const float* w_out = (const float*)d_in[3];
    const float* b_out = (const float*)d_in[4];
    float* out = (float*)d_out;

    char* ws = (char*)d_ws;
    unsigned short* qb    = (unsigned short*)ws;                        // 8 MB
    unsigned short* kb    = (unsigned short*)(ws + ((size_t)8  << 20)); // 8 MB
    unsigned short* vt    = (unsigned short*)(ws + ((size_t)16 << 20)); // 8 MB
    unsigned short* xb    = (unsigned short*)(ws + ((size_t)24 << 20)); // 8 MB (alias yb)
    unsigned short* yb    = xb;
    unsigned short* woutT = (unsigned short*)(ws + ((size_t)32 << 20)); // 2 MB
    unsigned short* vb    = (unsigned short*)(ws + ((size_t)34 << 20)); // 8 MB (dead after transp_v)
    unsigned short* wqkvT = (unsigned short*)(ws + ((size_t)42 << 20)); // 6 MB (dead after gemm_qkv)
    unsigned short* po    = (unsigned short*)(ws + ((size_t)34 << 20)); // 18 MB, aliases vb+wqkvT
    float*          pm    = (float*)(ws + ((size_t)52 << 20));          // 576 KB
    float*          pl    = (float*)(ws + ((size_t)52 << 20) + (640 << 10)); // 576 KB

    prep    <<<2048, 256, 0, stream>>>(x, xb, w_qkv, wqkvT, w_out, woutT);
    gemm_qkv<<<dim3(24, 32), 256, 0, stream>>>(xb, wqkvT, b_qkv, qb, kb, vb);
    transp_v<<<dim3(32, 32), 256, 0, stream>>>(vb, vt);
    attn_p1 <<<dim3(80, 32), 256, 0, stream>>>(qb, kb, vt, yb, po, pm, pl);
    attn_p2 <<<dim3(24, 32), 256, 0, stream>>>(po, pm, pl, yb);
    gemm_out<<<dim3(16, 32), 256, 0, stream>>>(yb, woutT, b_out, out);
}